// Round 1
// baseline (278.307 us; speedup 1.0000x reference)
//
#include <hip/hip_runtime.h>
#include <hip/hip_fp16.h>

#define DEV __device__ __forceinline__

typedef _Float16 f16x8 __attribute__((ext_vector_type(8)));
typedef float f32x4 __attribute__((ext_vector_type(4)));

DEV void gload16(void* lds, const void* g) {
  __builtin_amdgcn_global_load_lds((__attribute__((address_space(1))) const void*)g,
                                   (__attribute__((address_space(3))) void*)lds,
                                   16, 0, 0);
}

DEV f32x4 mfma16(f16x8 a, f16x8 b, f32x4 c) {
  return __builtin_amdgcn_mfma_f32_16x16x32_f16(a, b, c, 0, 0, 0);
}

// ---------------- W transpose + cast: Wt[n][k] = W[k][n] (f16) ----------------
__global__ __launch_bounds__(256) void transw_kernel(
    const float* __restrict__ W0, const float* __restrict__ W1,
    const float* __restrict__ W2, const float* __restrict__ W3,
    _Float16* __restrict__ Wt) {
  __shared__ float tile[32][33];
  const float* W = (blockIdx.z == 0) ? W0 : (blockIdx.z == 1) ? W1
                 : (blockIdx.z == 2) ? W2 : W3;
  _Float16* dst = Wt + (size_t)blockIdx.z * (1024 * 1024);
  const int tx = threadIdx.x & 31, ty = threadIdx.x >> 5;
  const int n0 = blockIdx.x * 32, k0 = blockIdx.y * 32;
#pragma unroll
  for (int i = 0; i < 4; ++i)
    tile[ty + i * 8][tx] = W[(size_t)(k0 + ty + i * 8) * 1024 + n0 + tx];
  __syncthreads();
#pragma unroll
  for (int i = 0; i < 4; ++i)
    dst[(size_t)(n0 + ty + i * 8) * 1024 + k0 + tx] = (_Float16)tile[tx][ty + i * 8];
}

// ---------------- GEMM: C = A(MxK) @ Bt(N,K)^T + bias ----------------
// 128x128 tile, BK=32, 256 threads = 4 waves (2x2 of 64x64 each).
// MODE 0: f16 out, head-layout (B,H,S,64).  MODE 1: f16 out, V-transposed (B,H,64,S).
// MODE 2: f32 out, plain (M,1024).  AF32: A is fp32 (reg-staged+cvt), else f16 via global_load_lds.
template <int MODE, bool AF32>
__global__ __launch_bounds__(256) void gemm_kernel(
    const void* __restrict__ Aptr, const _Float16* __restrict__ Bt,
    const float* __restrict__ bias, void* __restrict__ Cptr) {
  __shared__ __attribute__((aligned(16))) _Float16 Al[128 * 32];
  __shared__ __attribute__((aligned(16))) _Float16 Bl[128 * 32];
  const int t = threadIdx.x;
  const int l = t & 63, w = t >> 6;
  const int wr = w >> 1, wc = w & 1;
  const int lo = l & 15, lg = l >> 4;
  const int m0 = blockIdx.y * 128, n0 = blockIdx.x * 128;

  f32x4 acc[4][4];
#pragma unroll
  for (int i = 0; i < 4; ++i)
#pragma unroll
    for (int j = 0; j < 4; ++j) acc[i][j] = (f32x4){0.f, 0.f, 0.f, 0.f};

  for (int ks = 0; ks < 1024; ks += 32) {
    __syncthreads();
    gload16(&Bl[t * 8], Bt + (size_t)(n0 + (t >> 2)) * 1024 + ks + (t & 3) * 8);
    gload16(&Bl[(t + 256) * 8], Bt + (size_t)(n0 + (t >> 2) + 64) * 1024 + ks + (t & 3) * 8);
    if constexpr (AF32) {
      const float* Ag = (const float*)Aptr;
      const int row = t >> 1, c0 = (t & 1) * 16;
      const float4* src = (const float4*)(Ag + (size_t)(m0 + row) * 1024 + ks + c0);
      float4 f0 = src[0], f1 = src[1], f2 = src[2], f3 = src[3];
      f16x8 v0, v1;
      v0[0] = (_Float16)f0.x; v0[1] = (_Float16)f0.y; v0[2] = (_Float16)f0.z; v0[3] = (_Float16)f0.w;
      v0[4] = (_Float16)f1.x; v0[5] = (_Float16)f1.y; v0[6] = (_Float16)f1.z; v0[7] = (_Float16)f1.w;
      v1[0] = (_Float16)f2.x; v1[1] = (_Float16)f2.y; v1[2] = (_Float16)f2.z; v1[3] = (_Float16)f2.w;
      v1[4] = (_Float16)f3.x; v1[5] = (_Float16)f3.y; v1[6] = (_Float16)f3.z; v1[7] = (_Float16)f3.w;
      *reinterpret_cast<f16x8*>(&Al[row * 32 + c0]) = v0;
      *reinterpret_cast<f16x8*>(&Al[row * 32 + c0 + 8]) = v1;
    } else {
      const _Float16* Ag = (const _Float16*)Aptr;
      gload16(&Al[t * 8], Ag + (size_t)(m0 + (t >> 2)) * 1024 + ks + (t & 3) * 8);
      gload16(&Al[(t + 256) * 8], Ag + (size_t)(m0 + (t >> 2) + 64) * 1024 + ks + (t & 3) * 8);
    }
    __syncthreads();

    f16x8 af[4], bf[4];
#pragma unroll
    for (int mi = 0; mi < 4; ++mi)
      af[mi] = *reinterpret_cast<const f16x8*>(&Al[(wr * 64 + mi * 16 + lo) * 32 + lg * 8]);
#pragma unroll
    for (int ni = 0; ni < 4; ++ni)
      bf[ni] = *reinterpret_cast<const f16x8*>(&Bl[(wc * 64 + ni * 16 + lo) * 32 + lg * 8]);
#pragma unroll
    for (int mi = 0; mi < 4; ++mi)
#pragma unroll
      for (int ni = 0; ni < 4; ++ni)
        acc[mi][ni] = mfma16(af[mi], bf[ni], acc[mi][ni]);
  }

#pragma unroll
  for (int mi = 0; mi < 4; ++mi) {
#pragma unroll
    for (int ni = 0; ni < 4; ++ni) {
      const int col = n0 + wc * 64 + ni * 16 + lo;
      const int rowb = m0 + wr * 64 + mi * 16 + lg * 4;
      const float bc = bias[col];
#pragma unroll
      for (int r = 0; r < 4; ++r) {
        float v = acc[mi][ni][r] + bc;
        const int m = rowb + r;
        if constexpr (MODE == 2) {
          ((float*)Cptr)[(size_t)m * 1024 + col] = v;
        } else {
          const int b = m >> 10, s = m & 1023;
          const int h = col >> 6, d = col & 63;
          _Float16* C = (_Float16*)Cptr;
          if constexpr (MODE == 0)
            C[((size_t)(b * 16 + h) * 1024 + s) * 64 + d] = (_Float16)v;
          else
            C[((size_t)(b * 16 + h) * 64 + d) * 1024 + s] = (_Float16)v;
        }
      }
    }
  }
}

// ---------------- Flash attention ----------------
// grid (S/64, B*H), 256 threads = 4 waves; wave w owns q-rows [q0, q0+16).
// Qh,Kh: (B,H,S,64) f16.  Vt: (B,H,64,S) f16.  AO out: (B,S,1024) f16.
__global__ __launch_bounds__(256) void attn_kernel(
    const _Float16* __restrict__ Qh, const _Float16* __restrict__ Kh,
    const _Float16* __restrict__ Vt, const float* __restrict__ weight,
    const float* __restrict__ mask, _Float16* __restrict__ AO) {
  __shared__ __attribute__((aligned(16))) _Float16 Plds[4][16][72];
  const int t = threadIdx.x, l = t & 63, w = t >> 6;
  const int lo = l & 15, lg = l >> 4;
  const int bh = blockIdx.y, b = bh >> 4, h = bh & 15;
  const int q0 = blockIdx.x * 64 + w * 16;
  const float scale = (float)(0.1 + (double)h * (9.9 / 15.0));
  const _Float16* Qb = Qh + (size_t)bh * 1024 * 64;
  const _Float16* Kb = Kh + (size_t)bh * 1024 * 64;
  const _Float16* Vb = Vt + (size_t)bh * 64 * 1024;
  const float* Wb = weight + (size_t)b * 1024 * 1024;
  const float* Mb = mask + (size_t)b * 1024;
  const float L2E = 1.44269504089f;

  const f16x8 qf0 = *reinterpret_cast<const f16x8*>(Qb + (q0 + lo) * 64 + lg * 8);
  const f16x8 qf1 = *reinterpret_cast<const f16x8*>(Qb + (q0 + lo) * 64 + 32 + lg * 8);

  f32x4 oacc[4];
#pragma unroll
  for (int di = 0; di < 4; ++di) oacc[di] = (f32x4){0.f, 0.f, 0.f, 0.f};
  float mrun[4], lsum[4];
#pragma unroll
  for (int r = 0; r < 4; ++r) { mrun[r] = -3e38f; lsum[r] = 0.f; }
  const int qrow = q0 + lg * 4;

  for (int kt = 0; kt < 16; ++kt) {
    const int kv0 = kt * 64;
    float sv[4][4];
    float tm[4] = {-3e38f, -3e38f, -3e38f, -3e38f};
#pragma unroll
    for (int ni = 0; ni < 4; ++ni) {
      const int key = kv0 + ni * 16 + lo;
      f32x4 s = (f32x4){0.f, 0.f, 0.f, 0.f};
      f16x8 kf0 = *reinterpret_cast<const f16x8*>(Kb + key * 64 + lg * 8);
      f16x8 kf1 = *reinterpret_cast<const f16x8*>(Kb + key * 64 + 32 + lg * 8);
      s = mfma16(qf0, kf0, s);
      s = mfma16(qf1, kf1, s);
      const float mk = Mb[key] * -1e9f;
#pragma unroll
      for (int r = 0; r < 4; ++r) {
        const float wgt = Wb[(size_t)(qrow + r) * 1024 + key];
        const float x = s[r] * 0.125f + wgt * scale + mk;
        sv[ni][r] = x;
        tm[r] = fmaxf(tm[r], x);
      }
    }
#pragma unroll
    for (int st = 1; st < 16; st <<= 1)
#pragma unroll
      for (int r = 0; r < 4; ++r) tm[r] = fmaxf(tm[r], __shfl_xor(tm[r], st));
#pragma unroll
    for (int r = 0; r < 4; ++r) {
      const float mn = fmaxf(mrun[r], tm[r]);
      const float fr = exp2f((mrun[r] - mn) * L2E);
      mrun[r] = mn;
      lsum[r] *= fr;
      oacc[0][r] *= fr; oacc[1][r] *= fr; oacc[2][r] *= fr; oacc[3][r] *= fr;
    }
#pragma unroll
    for (int ni = 0; ni < 4; ++ni)
#pragma unroll
      for (int r = 0; r < 4; ++r) {
        const float p = exp2f((sv[ni][r] - mrun[r]) * L2E);
        lsum[r] += p;
        Plds[w][lg * 4 + r][ni * 16 + lo] = (_Float16)p;
      }
    const f16x8 pa0 = *reinterpret_cast<const f16x8*>(&Plds[w][lo][lg * 8]);
    const f16x8 pa1 = *reinterpret_cast<const f16x8*>(&Plds[w][lo][32 + lg * 8]);
#pragma unroll
    for (int di = 0; di < 4; ++di) {
      f16x8 vf0 = *reinterpret_cast<const f16x8*>(Vb + (size_t)(di * 16 + lo) * 1024 + kv0 + lg * 8);
      f16x8 vf1 = *reinterpret_cast<const f16x8*>(Vb + (size_t)(di * 16 + lo) * 1024 + kv0 + 32 + lg * 8);
      oacc[di] = mfma16(pa0, vf0, oacc[di]);
      oacc[di] = mfma16(pa1, vf1, oacc[di]);
    }
  }
#pragma unroll
  for (int st = 1; st < 16; st <<= 1)
#pragma unroll
    for (int r = 0; r < 4; ++r) lsum[r] += __shfl_xor(lsum[r], st);
#pragma unroll
  for (int r = 0; r < 4; ++r) {
    const float inv = 1.0f / lsum[r];
#pragma unroll
    for (int di = 0; di < 4; ++di)
      AO[((size_t)b * 1024 + qrow + r) * 1024 + h * 64 + di * 16 + lo] =
          (_Float16)(oacc[di][r] * inv);
  }
}

extern "C" void kernel_launch(void* const* d_in, const int* in_sizes, int n_in,
                              void* d_out, int out_size, void* d_ws, size_t ws_size,
                              hipStream_t stream) {
  (void)in_sizes; (void)n_in; (void)out_size; (void)ws_size;
  const float* v      = (const float*)d_in[0];
  const float* k      = (const float*)d_in[1];
  const float* q      = (const float*)d_in[2];
  const float* weight = (const float*)d_in[3];
  const float* mask   = (const float*)d_in[4];
  const float* Wq = (const float*)d_in[5];
  const float* bq = (const float*)d_in[6];
  const float* Wk = (const float*)d_in[7];
  const float* bk = (const float*)d_in[8];
  const float* Wv = (const float*)d_in[9];
  const float* bv = (const float*)d_in[10];
  const float* Wo = (const float*)d_in[11];
  const float* bo = (const float*)d_in[12];
  float* out = (float*)d_out;

  char* ws = (char*)d_ws;
  _Float16* Wt = (_Float16*)ws;                    // 4 x (1024x1024) f16 = 8 MB
  _Float16* Qh = (_Float16*)(ws + (8u << 20));     // (B,H,S,64) f16 = 8 MB
  _Float16* Kh = (_Float16*)(ws + (16u << 20));    // 8 MB
  _Float16* Vt = (_Float16*)(ws + (24u << 20));    // (B,H,64,S) f16 = 8 MB
  _Float16* AO = (_Float16*)(ws + (32u << 20));    // (B,S,1024) f16 = 8 MB

  transw_kernel<<<dim3(32, 32, 4), 256, 0, stream>>>(Wq, Wk, Wv, Wo, Wt);
  gemm_kernel<0, true><<<dim3(8, 32), 256, 0, stream>>>(q, Wt + 0 * (1 << 20), bq, Qh);
  gemm_kernel<0, true><<<dim3(8, 32), 256, 0, stream>>>(k, Wt + 1 * (1 << 20), bk, Kh);
  gemm_kernel<1, true><<<dim3(8, 32), 256, 0, stream>>>(v, Wt + 2 * (1 << 20), bv, Vt);
  attn_kernel<<<dim3(16, 64), 256, 0, stream>>>(Qh, Kh, Vt, weight, mask, AO);
  gemm_kernel<2, false><<<dim3(8, 32), 256, 0, stream>>>(AO, Wt + 3 * (1 << 20), bo, out);
}

// Round 2
// 260.483 us; speedup vs baseline: 1.0684x; 1.0684x over previous
//
#include <hip/hip_runtime.h>
#include <hip/hip_fp16.h>

#define DEV __device__ __forceinline__

typedef _Float16 f16x8 __attribute__((ext_vector_type(8)));
typedef _Float16 f16x4 __attribute__((ext_vector_type(4)));
typedef float f32x4 __attribute__((ext_vector_type(4)));

DEV void gload16(void* lds, const void* g) {
  __builtin_amdgcn_global_load_lds((__attribute__((address_space(1))) const void*)g,
                                   (__attribute__((address_space(3))) void*)lds,
                                   16, 0, 0);
}

DEV f32x4 mfma16(f16x8 a, f16x8 b, f32x4 c) {
  return __builtin_amdgcn_mfma_f32_16x16x32_f16(a, b, c, 0, 0, 0);
}

// ---------------- W transpose + cast: Wt[n][k] = W[k][n] (f16) ----------------
__global__ __launch_bounds__(256) void transw_kernel(
    const float* __restrict__ W0, const float* __restrict__ W1,
    const float* __restrict__ W2, const float* __restrict__ W3,
    _Float16* __restrict__ Wt) {
  __shared__ float tile[32][33];
  const float* W = (blockIdx.z == 0) ? W0 : (blockIdx.z == 1) ? W1
                 : (blockIdx.z == 2) ? W2 : W3;
  _Float16* dst = Wt + (size_t)blockIdx.z * (1024 * 1024);
  const int tx = threadIdx.x & 31, ty = threadIdx.x >> 5;
  const int n0 = blockIdx.x * 32, k0 = blockIdx.y * 32;
#pragma unroll
  for (int i = 0; i < 4; ++i)
    tile[ty + i * 8][tx] = W[(size_t)(k0 + ty + i * 8) * 1024 + n0 + tx];
  __syncthreads();
#pragma unroll
  for (int i = 0; i < 4; ++i)
    dst[(size_t)(n0 + ty + i * 8) * 1024 + k0 + tx] = (_Float16)tile[tx][ty + i * 8];
}

// ---------------- weight fp32 -> f16 cast ----------------
__global__ __launch_bounds__(256) void wcast_kernel(const float* __restrict__ W,
                                                    _Float16* __restrict__ Wh) {
  const size_t i = (size_t)(blockIdx.x * 256 + threadIdx.x) * 8;
  float4 a = *(const float4*)(W + i);
  float4 b = *(const float4*)(W + i + 4);
  f16x8 o;
  o[0] = (_Float16)a.x; o[1] = (_Float16)a.y; o[2] = (_Float16)a.z; o[3] = (_Float16)a.w;
  o[4] = (_Float16)b.x; o[5] = (_Float16)b.y; o[6] = (_Float16)b.z; o[7] = (_Float16)b.w;
  *(f16x8*)(Wh + i) = o;
}

// ---------------- shared GEMM core: C = A(MxK) @ Bt(N,K)^T ----------------
// BM x 128 tile, BK=32, 256 threads = 4 waves. BM=128 -> waves 2x2 (64x64 each,
// NI=4); BM=64 -> waves 1x4 (64x32 each, NI=2).
template <int BM, bool AF32>
DEV void gemm_core(const void* __restrict__ Aptr, const _Float16* __restrict__ Bt,
                   _Float16* Al, _Float16* Bl, int m0, int n0, f32x4 (&acc)[4][4]) {
  constexpr int WR = BM / 64, WC = 4 / WR, NI = (128 / WC) / 16;
  const int t = threadIdx.x;
  const int l = t & 63, w = t >> 6;
  const int wr = w / WC, wc = w % WC;
  const int lo = l & 15, lg = l >> 4;

  for (int ks = 0; ks < 1024; ks += 32) {
    __syncthreads();
    gload16(&Bl[t * 8], Bt + (size_t)(n0 + (t >> 2)) * 1024 + ks + (t & 3) * 8);
    gload16(&Bl[(t + 256) * 8], Bt + (size_t)(n0 + (t >> 2) + 64) * 1024 + ks + (t & 3) * 8);
    if constexpr (AF32) {
      const float* Ag = (const float*)Aptr;
      if constexpr (BM == 128) {
        const int row = t >> 1, c0 = (t & 1) * 16;
        const float4* src = (const float4*)(Ag + (size_t)(m0 + row) * 1024 + ks + c0);
        float4 f0 = src[0], f1 = src[1], f2 = src[2], f3 = src[3];
        f16x8 v0, v1;
        v0[0] = (_Float16)f0.x; v0[1] = (_Float16)f0.y; v0[2] = (_Float16)f0.z; v0[3] = (_Float16)f0.w;
        v0[4] = (_Float16)f1.x; v0[5] = (_Float16)f1.y; v0[6] = (_Float16)f1.z; v0[7] = (_Float16)f1.w;
        v1[0] = (_Float16)f2.x; v1[1] = (_Float16)f2.y; v1[2] = (_Float16)f2.z; v1[3] = (_Float16)f2.w;
        v1[4] = (_Float16)f3.x; v1[5] = (_Float16)f3.y; v1[6] = (_Float16)f3.z; v1[7] = (_Float16)f3.w;
        *(f16x8*)&Al[row * 32 + c0] = v0;
        *(f16x8*)&Al[row * 32 + c0 + 8] = v1;
      } else {
        const int row = t >> 2, c0 = (t & 3) * 8;
        const float4* src = (const float4*)(Ag + (size_t)(m0 + row) * 1024 + ks + c0);
        float4 f0 = src[0], f1 = src[1];
        f16x8 v0;
        v0[0] = (_Float16)f0.x; v0[1] = (_Float16)f0.y; v0[2] = (_Float16)f0.z; v0[3] = (_Float16)f0.w;
        v0[4] = (_Float16)f1.x; v0[5] = (_Float16)f1.y; v0[6] = (_Float16)f1.z; v0[7] = (_Float16)f1.w;
        *(f16x8*)&Al[row * 32 + c0] = v0;
      }
    } else {
      const _Float16* Ag = (const _Float16*)Aptr;
      gload16(&Al[t * 8], Ag + (size_t)(m0 + (t >> 2)) * 1024 + ks + (t & 3) * 8);
      if constexpr (BM == 128)
        gload16(&Al[(t + 256) * 8], Ag + (size_t)(m0 + (t >> 2) + 64) * 1024 + ks + (t & 3) * 8);
    }
    __syncthreads();

    f16x8 af[4], bf[NI];
#pragma unroll
    for (int mi = 0; mi < 4; ++mi)
      af[mi] = *(const f16x8*)&Al[(wr * 64 + mi * 16 + lo) * 32 + lg * 8];
#pragma unroll
    for (int ni = 0; ni < NI; ++ni)
      bf[ni] = *(const f16x8*)&Bl[(wc * (NI * 16) + ni * 16 + lo) * 32 + lg * 8];
#pragma unroll
    for (int mi = 0; mi < 4; ++mi)
#pragma unroll
      for (int ni = 0; ni < NI; ++ni)
        acc[mi][ni] = mfma16(af[mi], bf[ni], acc[mi][ni]);
  }
}

// ---------------- fused QKV projections (z = 0:Q, 1:K, 2:V) ----------------
__global__ __launch_bounds__(256) void proj_kernel(
    const float* __restrict__ qin, const float* __restrict__ kin,
    const float* __restrict__ vin, const _Float16* __restrict__ Wt,
    const float* __restrict__ bq, const float* __restrict__ bk,
    const float* __restrict__ bv, _Float16* __restrict__ Qh,
    _Float16* __restrict__ Kh, _Float16* __restrict__ Vh) {
  __shared__ __attribute__((aligned(16))) _Float16 Al[128 * 32];
  __shared__ __attribute__((aligned(16))) _Float16 Bl[128 * 32];
  const int z = blockIdx.z;
  const float* A = (z == 0) ? qin : (z == 1) ? kin : vin;
  const _Float16* Bt = Wt + (size_t)z * (1 << 20);
  const float* bias = (z == 0) ? bq : (z == 1) ? bk : bv;
  _Float16* C = (z == 0) ? Qh : (z == 1) ? Kh : Vh;
  const int m0 = blockIdx.y * 128, n0 = blockIdx.x * 128;

  f32x4 acc[4][4];
#pragma unroll
  for (int i = 0; i < 4; ++i)
#pragma unroll
    for (int j = 0; j < 4; ++j) acc[i][j] = (f32x4){0.f, 0.f, 0.f, 0.f};
  gemm_core<128, true>(A, Bt, Al, Bl, m0, n0, acc);

  const int l = threadIdx.x & 63, w = threadIdx.x >> 6;
  const int wr = w >> 1, wc = w & 1;
  const int lo = l & 15, lg = l >> 4;
#pragma unroll
  for (int mi = 0; mi < 4; ++mi) {
#pragma unroll
    for (int ni = 0; ni < 4; ++ni) {
      const int col = n0 + wc * 64 + ni * 16 + lo;
      const int rowb = m0 + wr * 64 + mi * 16 + lg * 4;
      const float bc = bias[col];
      const int h = col >> 6, d = col & 63;
#pragma unroll
      for (int r = 0; r < 4; ++r) {
        const float vv = acc[mi][ni][r] + bc;
        const int m = rowb + r;
        const int b = m >> 10, s = m & 1023;
        if (z < 2)
          C[((size_t)(b * 16 + h) * 1024 + s) * 64 + d] = (_Float16)vv;
        else
          C[((size_t)(b * 16 + h) * 64 + d) * 1024 + s] = (_Float16)vv;
      }
    }
  }
}

// ---------------- output projection: out(f32) = AO @ Wo^T + bo ----------------
__global__ __launch_bounds__(256) void outproj_kernel(
    const _Float16* __restrict__ AO, const _Float16* __restrict__ Bt,
    const float* __restrict__ bias, float* __restrict__ out) {
  __shared__ __attribute__((aligned(16))) _Float16 Al[64 * 32];
  __shared__ __attribute__((aligned(16))) _Float16 Bl[128 * 32];
  const int m0 = blockIdx.y * 64, n0 = blockIdx.x * 128;
  f32x4 acc[4][4];
#pragma unroll
  for (int i = 0; i < 4; ++i)
#pragma unroll
    for (int j = 0; j < 4; ++j) acc[i][j] = (f32x4){0.f, 0.f, 0.f, 0.f};
  gemm_core<64, false>(AO, Bt, Al, Bl, m0, n0, acc);

  const int l = threadIdx.x & 63, w = threadIdx.x >> 6;
  const int wc = w;  // WR=1, WC=4
  const int lo = l & 15, lg = l >> 4;
#pragma unroll
  for (int mi = 0; mi < 4; ++mi) {
#pragma unroll
    for (int ni = 0; ni < 2; ++ni) {
      const int col = n0 + wc * 32 + ni * 16 + lo;
      const int rowb = m0 + mi * 16 + lg * 4;
      const float bc = bias[col];
#pragma unroll
      for (int r = 0; r < 4; ++r)
        out[(size_t)(rowb + r) * 1024 + col] = acc[mi][ni][r] + bc;
    }
  }
}

// ---------------- Flash attention, swapped-QK orientation ----------------
// grid (S/64, B*H [, NSPLIT]); 256 threads = 4 waves, wave w owns q-rows
// [q0, q0+16).  Scores computed as mfma(K,Q): lane holds q = q0+lo,
// keys key0 + lg*4 + r  ->  bias is a vector load per lane.
template <bool SPLIT>
__global__ __launch_bounds__(256) void attn_kernel(
    const _Float16* __restrict__ Qh, const _Float16* __restrict__ Kh,
    const _Float16* __restrict__ Vh, const void* __restrict__ Wptr,
    const float* __restrict__ mask, void* __restrict__ Oout,
    float2* __restrict__ Sst) {
  __shared__ __attribute__((aligned(16))) _Float16 Pl[4][16][72];
  const int t = threadIdx.x, l = t & 63, w = t >> 6;
  const int lo = l & 15, lg = l >> 4;
  const int bh = blockIdx.y, b = bh >> 4, h = bh & 15;
  const int q0 = blockIdx.x * 64 + w * 16;
  const int sp = SPLIT ? blockIdx.z : 0;
  const int nkt = SPLIT ? 8 : 16;
  const int kvbase = sp * 512;
  constexpr float L2E = 1.44269504089f;
  const float scale = 0.1f + (float)h * (9.9f / 15.0f);
  const float cS = 0.125f * L2E;
  const float cW = scale * L2E;
  const float cM = -1e9f * L2E;
  const _Float16* Qb = Qh + (size_t)bh * (1024 * 64);
  const _Float16* Kb = Kh + (size_t)bh * (1024 * 64);
  const _Float16* Vb = Vh + (size_t)bh * (64 * 1024);
  const float* Mb = mask + (size_t)b * 1024;

  const f16x8 qf0 = *(const f16x8*)(Qb + (q0 + lo) * 64 + lg * 8);
  const f16x8 qf1 = *(const f16x8*)(Qb + (q0 + lo) * 64 + 32 + lg * 8);

  f32x4 oacc[4];
#pragma unroll
  for (int di = 0; di < 4; ++di) oacc[di] = (f32x4){0.f, 0.f, 0.f, 0.f};
  float mrun = -1e38f, lsum = 0.f;

  for (int kt = 0; kt < nkt; ++kt) {
    const int kv0 = kvbase + kt * 64;
    float sv[4][4];
    float tmax = -1e38f;
#pragma unroll
    for (int ni = 0; ni < 4; ++ni) {
      const int key0 = kv0 + ni * 16;
      f16x8 kf0 = *(const f16x8*)(Kb + (size_t)(key0 + lo) * 64 + lg * 8);
      f16x8 kf1 = *(const f16x8*)(Kb + (size_t)(key0 + lo) * 64 + 32 + lg * 8);
      f32x4 s = (f32x4){0.f, 0.f, 0.f, 0.f};
      s = mfma16(kf0, qf0, s);  // D[key][q]: col=lo->q, row=lg*4+r->key
      s = mfma16(kf1, qf1, s);
      const float4 m4 = *(const float4*)(Mb + key0 + lg * 4);
      float wgt[4];
      if constexpr (SPLIT) {
        const f16x4 wv = *(const f16x4*)((const _Float16*)Wptr + ((size_t)b << 20) +
                                         (size_t)(q0 + lo) * 1024 + key0 + lg * 4);
        wgt[0] = (float)wv[0]; wgt[1] = (float)wv[1];
        wgt[2] = (float)wv[2]; wgt[3] = (float)wv[3];
      } else {
        const float4 wv = *(const float4*)((const float*)Wptr + ((size_t)b << 20) +
                                           (size_t)(q0 + lo) * 1024 + key0 + lg * 4);
        wgt[0] = wv.x; wgt[1] = wv.y; wgt[2] = wv.z; wgt[3] = wv.w;
      }
      const float mm[4] = {m4.x, m4.y, m4.z, m4.w};
#pragma unroll
      for (int r = 0; r < 4; ++r) {
        const float x = s[r] * cS + wgt[r] * cW + mm[r] * cM;  // log2 units
        sv[ni][r] = x;
        tmax = fmaxf(tmax, x);
      }
    }
    // prefetch V (independent of softmax) to overlap HBM latency with VALU
    f16x8 vf0[4], vf1[4];
#pragma unroll
    for (int di = 0; di < 4; ++di) {
      vf0[di] = *(const f16x8*)(Vb + (size_t)(di * 16 + lo) * 1024 + kv0 + lg * 8);
      vf1[di] = *(const f16x8*)(Vb + (size_t)(di * 16 + lo) * 1024 + kv0 + 32 + lg * 8);
    }
    tmax = fmaxf(tmax, __shfl_xor(tmax, 16));
    tmax = fmaxf(tmax, __shfl_xor(tmax, 32));
    const float mn = fmaxf(mrun, tmax);
    const float fr = exp2f(mrun - mn);
    mrun = mn;
    float ps = 0.f;
    f16x4 pf[4];
#pragma unroll
    for (int ni = 0; ni < 4; ++ni)
#pragma unroll
      for (int r = 0; r < 4; ++r) {
        const float p = exp2f(sv[ni][r] - mn);
        ps += p;
        pf[ni][r] = (_Float16)p;
      }
    lsum = lsum * fr + ps;
#pragma unroll
    for (int r = 0; r < 4; ++r) {
      const float fro = __shfl(fr, lg * 4 + r);  // rescale for output row lg*4+r
      oacc[0][r] *= fro; oacc[1][r] *= fro; oacc[2][r] *= fro; oacc[3][r] *= fro;
    }
#pragma unroll
    for (int ni = 0; ni < 4; ++ni)
      *(f16x4*)(&Pl[w][lo][ni * 16 + lg * 4]) = pf[ni];
    const f16x8 pa0 = *(const f16x8*)(&Pl[w][lo][lg * 8]);
    const f16x8 pa1 = *(const f16x8*)(&Pl[w][lo][32 + lg * 8]);
#pragma unroll
    for (int di = 0; di < 4; ++di) {
      oacc[di] = mfma16(pa0, vf0[di], oacc[di]);
      oacc[di] = mfma16(pa1, vf1[di], oacc[di]);
    }
  }
  lsum += __shfl_xor(lsum, 16);
  lsum += __shfl_xor(lsum, 32);
  float linv[4];
#pragma unroll
  for (int r = 0; r < 4; ++r) linv[r] = 1.f / __shfl(lsum, lg * 4 + r);

  if constexpr (SPLIT) {
    if (lg == 0) Sst[(size_t)sp * 65536 + bh * 1024 + q0 + lo] = make_float2(mrun, lsum);
    _Float16* Op = (_Float16*)Oout + (size_t)sp * (64ull * 1024 * 64);
#pragma unroll
    for (int r = 0; r < 4; ++r)
#pragma unroll
      for (int di = 0; di < 4; ++di)
        Op[((size_t)bh * 1024 + q0 + lg * 4 + r) * 64 + di * 16 + lo] =
            (_Float16)(oacc[di][r] * linv[r]);
  } else {
    _Float16* AO = (_Float16*)Oout;
#pragma unroll
    for (int r = 0; r < 4; ++r)
#pragma unroll
      for (int di = 0; di < 4; ++di)
        AO[((size_t)(b * 1024) + q0 + lg * 4 + r) * 1024 + h * 64 + di * 16 + lo] =
            (_Float16)(oacc[di][r] * linv[r]);
  }
}

// ---------------- merge two KV-split partials -> AO ----------------
__global__ __launch_bounds__(256) void merge_kernel(
    const _Float16* __restrict__ Op, const float2* __restrict__ Sst,
    _Float16* __restrict__ AO) {
  const int idx = blockIdx.x * 256 + threadIdx.x;  // 1M threads, 4 d-elems each
  const int dc = idx & 15;
  const int qq = (idx >> 4) & 1023;
  const int bh = idx >> 14;
  const int b = bh >> 4, h = bh & 15;
  const float2 s1 = Sst[bh * 1024 + qq];
  const float2 s2 = Sst[65536 + bh * 1024 + qq];
  const float m = fmaxf(s1.x, s2.x);
  float w1 = exp2f(s1.x - m) * s1.y;
  float w2 = exp2f(s2.x - m) * s2.y;
  const float inv = 1.f / (w1 + w2);
  w1 *= inv; w2 *= inv;
  const size_t o = ((size_t)bh * 1024 + qq) * 64 + dc * 4;
  const f16x4 o1 = *(const f16x4*)(Op + o);
  const f16x4 o2 = *(const f16x4*)(Op + (64ull * 1024 * 64) + o);
  f16x4 r;
#pragma unroll
  for (int j = 0; j < 4; ++j)
    r[j] = (_Float16)(w1 * (float)o1[j] + w2 * (float)o2[j]);
  *(f16x4*)(AO + ((size_t)(b * 1024 + qq) * 1024 + h * 64 + dc * 4)) = r;
}

extern "C" void kernel_launch(void* const* d_in, const int* in_sizes, int n_in,
                              void* d_out, int out_size, void* d_ws, size_t ws_size,
                              hipStream_t stream) {
  (void)in_sizes; (void)n_in; (void)out_size;
  const float* v      = (const float*)d_in[0];
  const float* k      = (const float*)d_in[1];
  const float* q      = (const float*)d_in[2];
  const float* weight = (const float*)d_in[3];
  const float* mask   = (const float*)d_in[4];
  const float* Wq = (const float*)d_in[5];
  const float* bq = (const float*)d_in[6];
  const float* Wk = (const float*)d_in[7];
  const float* bk = (const float*)d_in[8];
  const float* Wv = (const float*)d_in[9];
  const float* bv = (const float*)d_in[10];
  const float* Wo = (const float*)d_in[11];
  const float* bo = (const float*)d_in[12];
  float* out = (float*)d_out;

  const size_t MB = 1ull << 20;
  char* ws = (char*)d_ws;
  _Float16* Wt = (_Float16*)ws;                 // 4 x 1M f16 = 8 MB
  _Float16* Qh = (_Float16*)(ws + 8 * MB);      // (B,H,S,64) f16, 8 MB
  _Float16* Kh = (_Float16*)(ws + 16 * MB);     // 8 MB
  _Float16* Vh = (_Float16*)(ws + 24 * MB);     // (B,H,64,S) f16, 8 MB

  transw_kernel<<<dim3(32, 32, 4), 256, 0, stream>>>(Wq, Wk, Wv, Wo, Wt);
  proj_kernel<<<dim3(8, 32, 3), 256, 0, stream>>>(q, k, v, Wt, bq, bk, bv, Qh, Kh, Vh);

  if (ws_size >= 57 * MB) {
    _Float16* Wh  = (_Float16*)(ws + 32 * MB);  // weight f16, 8 MB
    _Float16* Op  = (_Float16*)(ws + 40 * MB);  // 2 x (64,1024,64) f16 = 16 MB
    float2*   Sst = (float2*)(ws + 56 * MB);    // 2 x 64K float2 = 1 MB
    _Float16* AO  = Qh;                          // alias: Qh dead after attn
    wcast_kernel<<<2048, 256, 0, stream>>>(weight, Wh);
    attn_kernel<true><<<dim3(16, 64, 2), 256, 0, stream>>>(Qh, Kh, Vh, Wh, mask, Op, Sst);
    merge_kernel<<<4096, 256, 0, stream>>>(Op, Sst, AO);
    outproj_kernel<<<dim3(8, 64), 256, 0, stream>>>(AO, Wt + 3 * (1 << 20), bo, out);
  } else {
    _Float16* AO = (_Float16*)(ws + 32 * MB);   // 8 MB (total 40 MB)
    attn_kernel<false><<<dim3(16, 64), 256, 0, stream>>>(Qh, Kh, Vh, weight, mask, AO, nullptr);
    outproj_kernel<<<dim3(8, 64), 256, 0, stream>>>(AO, Wt + 3 * (1 << 20), bo, out);
  }
}

// Round 3
// 174.504 us; speedup vs baseline: 1.5949x; 1.4927x over previous
//
#include <hip/hip_runtime.h>
#include <hip/hip_fp16.h>

#define DEV __device__ __forceinline__

typedef _Float16 f16x8 __attribute__((ext_vector_type(8)));
typedef float f32x4 __attribute__((ext_vector_type(4)));

DEV void gload16(void* lds, const void* g) {
  __builtin_amdgcn_global_load_lds((__attribute__((address_space(1))) const void*)g,
                                   (__attribute__((address_space(3))) void*)lds,
                                   16, 0, 0);
}

DEV f32x4 mfma16(f16x8 a, f16x8 b, f32x4 c) {
  return __builtin_amdgcn_mfma_f32_16x16x32_f16(a, b, c, 0, 0, 0);
}

// ---------------- W transpose + cast: Wt[n][k] = W[k][n] (f16) ----------------
__global__ __launch_bounds__(256) void transw_kernel(
    const float* __restrict__ W0, const float* __restrict__ W1,
    const float* __restrict__ W2, const float* __restrict__ W3,
    _Float16* __restrict__ Wt) {
  __shared__ float tile[32][33];
  const float* W = (blockIdx.z == 0) ? W0 : (blockIdx.z == 1) ? W1
                 : (blockIdx.z == 2) ? W2 : W3;
  _Float16* dst = Wt + (size_t)blockIdx.z * (1024 * 1024);
  const int tx = threadIdx.x & 31, ty = threadIdx.x >> 5;
  const int n0 = blockIdx.x * 32, k0 = blockIdx.y * 32;
#pragma unroll
  for (int i = 0; i < 4; ++i)
    tile[ty + i * 8][tx] = W[(size_t)(k0 + ty + i * 8) * 1024 + n0 + tx];
  __syncthreads();
#pragma unroll
  for (int i = 0; i < 4; ++i)
    dst[(size_t)(n0 + ty + i * 8) * 1024 + k0 + tx] = (_Float16)tile[tx][ty + i * 8];
}

// ---------------- weight fp32 -> f16 cast ----------------
__global__ __launch_bounds__(256) void wcast_kernel(const float* __restrict__ W,
                                                    _Float16* __restrict__ Wh) {
  const size_t i = (size_t)(blockIdx.x * 256 + threadIdx.x) * 8;
  float4 a = *(const float4*)(W + i);
  float4 b = *(const float4*)(W + i + 4);
  f16x8 o;
  o[0] = (_Float16)a.x; o[1] = (_Float16)a.y; o[2] = (_Float16)a.z; o[3] = (_Float16)a.w;
  o[4] = (_Float16)b.x; o[5] = (_Float16)b.y; o[6] = (_Float16)b.z; o[7] = (_Float16)b.w;
  *(f16x8*)(Wh + i) = o;
}

// ---------------- shared GEMM core: C = A(MxK) @ Bt(N,K)^T ----------------
template <int BM, bool AF32>
DEV void gemm_core(const void* __restrict__ Aptr, const _Float16* __restrict__ Bt,
                   _Float16* Al, _Float16* Bl, int m0, int n0, f32x4 (&acc)[4][4]) {
  constexpr int WR = BM / 64, WC = 4 / WR, NI = (128 / WC) / 16;
  const int t = threadIdx.x;
  const int l = t & 63, w = t >> 6;
  const int wr = w / WC, wc = w % WC;
  const int lo = l & 15, lg = l >> 4;

  for (int ks = 0; ks < 1024; ks += 32) {
    __syncthreads();
    gload16(&Bl[t * 8], Bt + (size_t)(n0 + (t >> 2)) * 1024 + ks + (t & 3) * 8);
    gload16(&Bl[(t + 256) * 8], Bt + (size_t)(n0 + (t >> 2) + 64) * 1024 + ks + (t & 3) * 8);
    if constexpr (AF32) {
      const float* Ag = (const float*)Aptr;
      if constexpr (BM == 128) {
        const int row = t >> 1, c0 = (t & 1) * 16;
        const float4* src = (const float4*)(Ag + (size_t)(m0 + row) * 1024 + ks + c0);
        float4 f0 = src[0], f1 = src[1], f2 = src[2], f3 = src[3];
        f16x8 v0, v1;
        v0[0] = (_Float16)f0.x; v0[1] = (_Float16)f0.y; v0[2] = (_Float16)f0.z; v0[3] = (_Float16)f0.w;
        v0[4] = (_Float16)f1.x; v0[5] = (_Float16)f1.y; v0[6] = (_Float16)f1.z; v0[7] = (_Float16)f1.w;
        v1[0] = (_Float16)f2.x; v1[1] = (_Float16)f2.y; v1[2] = (_Float16)f2.z; v1[3] = (_Float16)f2.w;
        v1[4] = (_Float16)f3.x; v1[5] = (_Float16)f3.y; v1[6] = (_Float16)f3.z; v1[7] = (_Float16)f3.w;
        *(f16x8*)&Al[row * 32 + c0] = v0;
        *(f16x8*)&Al[row * 32 + c0 + 8] = v1;
      } else {
        const int row = t >> 2, c0 = (t & 3) * 8;
        const float4* src = (const float4*)(Ag + (size_t)(m0 + row) * 1024 + ks + c0);
        float4 f0 = src[0], f1 = src[1];
        f16x8 v0;
        v0[0] = (_Float16)f0.x; v0[1] = (_Float16)f0.y; v0[2] = (_Float16)f0.z; v0[3] = (_Float16)f0.w;
        v0[4] = (_Float16)f1.x; v0[5] = (_Float16)f1.y; v0[6] = (_Float16)f1.z; v0[7] = (_Float16)f1.w;
        *(f16x8*)&Al[row * 32 + c0] = v0;
      }
    } else {
      const _Float16* Ag = (const _Float16*)Aptr;
      gload16(&Al[t * 8], Ag + (size_t)(m0 + (t >> 2)) * 1024 + ks + (t & 3) * 8);
      if constexpr (BM == 128)
        gload16(&Al[(t + 256) * 8], Ag + (size_t)(m0 + (t >> 2) + 64) * 1024 + ks + (t & 3) * 8);
    }
    __syncthreads();

    f16x8 af[4], bf[NI];
#pragma unroll
    for (int mi = 0; mi < 4; ++mi)
      af[mi] = *(const f16x8*)&Al[(wr * 64 + mi * 16 + lo) * 32 + lg * 8];
#pragma unroll
    for (int ni = 0; ni < NI; ++ni)
      bf[ni] = *(const f16x8*)&Bl[(wc * (NI * 16) + ni * 16 + lo) * 32 + lg * 8];
#pragma unroll
    for (int mi = 0; mi < 4; ++mi)
#pragma unroll
      for (int ni = 0; ni < NI; ++ni)
        acc[mi][ni] = mfma16(af[mi], bf[ni], acc[mi][ni]);
  }
}

// ---------------- fused QKV projections (z = 0:Q, 1:K, 2:V) ----------------
// Qh plain (B,H,S,64).  Kt: per-(b,h) slab of 16 swizzled 64x64 tiles
// (row-major rows, 16B slots XOR-swizzled by row&7).  Vt: same but V^T
// (rows = d, cols = s within tile).
__global__ __launch_bounds__(256) void proj_kernel(
    const float* __restrict__ qin, const float* __restrict__ kin,
    const float* __restrict__ vin, const _Float16* __restrict__ Wt,
    const float* __restrict__ bq, const float* __restrict__ bk,
    const float* __restrict__ bv, _Float16* __restrict__ Qh,
    _Float16* __restrict__ Kt, _Float16* __restrict__ Vt) {
  __shared__ __attribute__((aligned(16))) _Float16 Al[128 * 32];
  __shared__ __attribute__((aligned(16))) _Float16 Bl[128 * 32];
  const int z = blockIdx.z;
  const float* A = (z == 0) ? qin : (z == 1) ? kin : vin;
  const _Float16* Bt = Wt + (size_t)z * (1 << 20);
  const float* bias = (z == 0) ? bq : (z == 1) ? bk : bv;
  _Float16* C = (z == 0) ? Qh : (z == 1) ? Kt : Vt;
  const int m0 = blockIdx.y * 128, n0 = blockIdx.x * 128;

  f32x4 acc[4][4];
#pragma unroll
  for (int i = 0; i < 4; ++i)
#pragma unroll
    for (int j = 0; j < 4; ++j) acc[i][j] = (f32x4){0.f, 0.f, 0.f, 0.f};
  gemm_core<128, true>(A, Bt, Al, Bl, m0, n0, acc);

  const int l = threadIdx.x & 63, w = threadIdx.x >> 6;
  const int wr = w >> 1, wc = w & 1;
  const int lo = l & 15, lg = l >> 4;
#pragma unroll
  for (int mi = 0; mi < 4; ++mi) {
#pragma unroll
    for (int ni = 0; ni < 4; ++ni) {
      const int col = n0 + wc * 64 + ni * 16 + lo;
      const int rowb = m0 + wr * 64 + mi * 16 + lg * 4;
      const float bc = bias[col];
      const int h = col >> 6, d = col & 63;
#pragma unroll
      for (int r = 0; r < 4; ++r) {
        const float vv = acc[mi][ni][r] + bc;
        const int m = rowb + r;
        const int b = m >> 10, s = m & 1023;
        const size_t slab = (size_t)(b * 16 + h) * 65536;
        if (z == 0) {
          C[slab + (size_t)s * 64 + d] = (_Float16)vv;
        } else if (z == 1) {
          // K tile: row = s&63, elem d at slot (d>>3)^(row&7)
          C[slab + (size_t)(s >> 6) * 4096 + (size_t)(s & 63) * 64 +
            (((d >> 3) ^ (s & 7)) << 3) + (d & 7)] = (_Float16)vv;
        } else {
          // V^T tile: row = d, col c = s&63 at slot (c>>3)^(d&7)
          C[slab + (size_t)(s >> 6) * 4096 + (size_t)d * 64 +
            ((((s >> 3) & 7) ^ (d & 7)) << 3) + (s & 7)] = (_Float16)vv;
        }
      }
    }
  }
}

// ---------------- output projection: out(f32) = AO @ Wo^T + bo ----------------
__global__ __launch_bounds__(256) void outproj_kernel(
    const _Float16* __restrict__ AO, const _Float16* __restrict__ Bt,
    const float* __restrict__ bias, float* __restrict__ out) {
  __shared__ __attribute__((aligned(16))) _Float16 Al[64 * 32];
  __shared__ __attribute__((aligned(16))) _Float16 Bl[128 * 32];
  const int m0 = blockIdx.y * 64, n0 = blockIdx.x * 128;
  f32x4 acc[4][4];
#pragma unroll
  for (int i = 0; i < 4; ++i)
#pragma unroll
    for (int j = 0; j < 4; ++j) acc[i][j] = (f32x4){0.f, 0.f, 0.f, 0.f};
  gemm_core<64, false>(AO, Bt, Al, Bl, m0, n0, acc);

  const int l = threadIdx.x & 63, w = threadIdx.x >> 6;
  const int wc = w;  // WR=1, WC=4
  const int lo = l & 15, lg = l >> 4;
#pragma unroll
  for (int mi = 0; mi < 4; ++mi) {
#pragma unroll
    for (int ni = 0; ni < 2; ++ni) {
      const int col = n0 + wc * 32 + ni * 16 + lo;
      const int rowb = m0 + mi * 16 + lg * 4;
      const float bc = bias[col];
#pragma unroll
      for (int r = 0; r < 4; ++r)
        out[(size_t)(rowb + r) * 1024 + col] = acc[mi][ni][r] + bc;
    }
  }
}

// ---------------- Flash attention v3 ----------------
// grid (S/128, B*H), 512 threads = 8 waves; wave w owns q-rows [q0w, q0w+16).
// K/V tiles staged in LDS (swizzled layout from proj), double-buffered,
// shared by all 8 waves.  q-major scores: lane (lg,lo) holds
// S[q = q0w + lg*4 + r][key = ni*16 + lo].
__global__ __launch_bounds__(512, 4) void attn_kernel(
    const _Float16* __restrict__ Qh, const _Float16* __restrict__ Kt,
    const _Float16* __restrict__ Vt, const _Float16* __restrict__ Wh,
    const float* __restrict__ mask, _Float16* __restrict__ AO) {
  __shared__ __attribute__((aligned(16))) _Float16 Kl[2][4096];
  __shared__ __attribute__((aligned(16))) _Float16 Vl[2][4096];
  __shared__ __attribute__((aligned(16))) _Float16 Pl[8][16][72];
  const int t = threadIdx.x, l = t & 63, w = t >> 6;
  const int lo = l & 15, lg = l >> 4;
  const int bh = blockIdx.y, b = bh >> 4, h = bh & 15;
  const int q0w = blockIdx.x * 128 + w * 16;
  constexpr float L2E = 1.44269504089f;
  const float scale = 0.1f + (float)h * (9.9f / 15.0f);
  const float cS = 0.125f * L2E;
  const float cW = scale * L2E;
  const float cM = -1e9f * L2E;
  const _Float16* Kslab = Kt + (size_t)bh * 65536;
  const _Float16* Vslab = Vt + (size_t)bh * 65536;
  const _Float16* Wb = Wh + ((size_t)b << 20);
  const float* Mb = mask + (size_t)b * 1024;
  const int qrow = q0w + lg * 4;

  const f16x8 qf0 = *(const f16x8*)(Qh + (size_t)bh * 65536 + (q0w + lo) * 64 + lg * 8);
  const f16x8 qf1 = *(const f16x8*)(Qh + (size_t)bh * 65536 + (q0w + lo) * 64 + 32 + lg * 8);

  f32x4 oacc[4];
#pragma unroll
  for (int di = 0; di < 4; ++di) oacc[di] = (f32x4){0.f, 0.f, 0.f, 0.f};
  float mrun[4], lsum[4];
#pragma unroll
  for (int r = 0; r < 4; ++r) { mrun[r] = -1e38f; lsum[r] = 0.f; }

  // prologue: stage tile 0
  gload16(&Kl[0][t * 8], Kslab + t * 8);
  gload16(&Vl[0][t * 8], Vslab + t * 8);
  __syncthreads();

  for (int kt = 0; kt < 16; ++kt) {
    const int cur = kt & 1;
    if (kt + 1 < 16) {
      gload16(&Kl[cur ^ 1][t * 8], Kslab + (size_t)(kt + 1) * 4096 + t * 8);
      gload16(&Vl[cur ^ 1][t * 8], Vslab + (size_t)(kt + 1) * 4096 + t * 8);
    }
    const int kv0 = kt * 64;
    const _Float16* Kb = Kl[cur];
    const _Float16* Vb = Vl[cur];
    const int sl = lg ^ (lo & 7);

    float sv[4][4];
    float tm[4] = {-1e38f, -1e38f, -1e38f, -1e38f};
#pragma unroll
    for (int ni = 0; ni < 4; ++ni) {
      const int key = kv0 + ni * 16 + lo;
      const float mkv = Mb[key] * cM;
      float wgt[4];
#pragma unroll
      for (int r = 0; r < 4; ++r)
        wgt[r] = (float)Wb[(size_t)(qrow + r) * 1024 + key];
      const int kr = ni * 16 + lo;
      f16x8 kf0 = *(const f16x8*)(Kb + kr * 64 + sl * 8);
      f16x8 kf1 = *(const f16x8*)(Kb + kr * 64 + (sl ^ 4) * 8);
      f32x4 s = (f32x4){0.f, 0.f, 0.f, 0.f};
      s = mfma16(qf0, kf0, s);
      s = mfma16(qf1, kf1, s);
#pragma unroll
      for (int r = 0; r < 4; ++r) {
        const float x = s[r] * cS + wgt[r] * cW + mkv;  // log2 units
        sv[ni][r] = x;
        tm[r] = fmaxf(tm[r], x);
      }
    }
#pragma unroll
    for (int st = 1; st < 16; st <<= 1)
#pragma unroll
      for (int r = 0; r < 4; ++r) tm[r] = fmaxf(tm[r], __shfl_xor(tm[r], st));
    float fr[4];
#pragma unroll
    for (int r = 0; r < 4; ++r) {
      const float mn = fmaxf(mrun[r], tm[r]);
      fr[r] = exp2f(mrun[r] - mn);
      mrun[r] = mn;
      lsum[r] *= fr[r];
    }
#pragma unroll
    for (int di = 0; di < 4; ++di)
#pragma unroll
      for (int r = 0; r < 4; ++r) oacc[di][r] *= fr[r];
#pragma unroll
    for (int ni = 0; ni < 4; ++ni)
#pragma unroll
      for (int r = 0; r < 4; ++r) {
        const float p = exp2f(sv[ni][r] - mrun[r]);
        lsum[r] += p;
        Pl[w][lg * 4 + r][ni * 16 + lo] = (_Float16)p;
      }
    const f16x8 pa0 = *(const f16x8*)(&Pl[w][lo][lg * 8]);
    const f16x8 pa1 = *(const f16x8*)(&Pl[w][lo][32 + lg * 8]);
    __builtin_amdgcn_s_setprio(1);
#pragma unroll
    for (int di = 0; di < 4; ++di) {
      const int d = di * 16 + lo;
      f16x8 vf0 = *(const f16x8*)(Vb + d * 64 + sl * 8);
      f16x8 vf1 = *(const f16x8*)(Vb + d * 64 + (sl ^ 4) * 8);
      oacc[di] = mfma16(pa0, vf0, oacc[di]);
      oacc[di] = mfma16(pa1, vf1, oacc[di]);
    }
    __builtin_amdgcn_s_setprio(0);
    __syncthreads();
  }

#pragma unroll
  for (int st = 1; st < 16; st <<= 1)
#pragma unroll
    for (int r = 0; r < 4; ++r) lsum[r] += __shfl_xor(lsum[r], st);
#pragma unroll
  for (int r = 0; r < 4; ++r) {
    const float inv = 1.0f / lsum[r];
#pragma unroll
    for (int di = 0; di < 4; ++di)
      AO[((size_t)(b * 1024) + qrow + r) * 1024 + h * 64 + di * 16 + lo] =
          (_Float16)(oacc[di][r] * inv);
  }
}

extern "C" void kernel_launch(void* const* d_in, const int* in_sizes, int n_in,
                              void* d_out, int out_size, void* d_ws, size_t ws_size,
                              hipStream_t stream) {
  (void)in_sizes; (void)n_in; (void)out_size; (void)ws_size;
  const float* v      = (const float*)d_in[0];
  const float* k      = (const float*)d_in[1];
  const float* q      = (const float*)d_in[2];
  const float* weight = (const float*)d_in[3];
  const float* mask   = (const float*)d_in[4];
  const float* Wq = (const float*)d_in[5];
  const float* bq = (const float*)d_in[6];
  const float* Wk = (const float*)d_in[7];
  const float* bk = (const float*)d_in[8];
  const float* Wv = (const float*)d_in[9];
  const float* bv = (const float*)d_in[10];
  const float* Wo = (const float*)d_in[11];
  const float* bo = (const float*)d_in[12];
  float* out = (float*)d_out;

  const size_t MB = 1ull << 20;
  char* ws = (char*)d_ws;
  _Float16* Wt = (_Float16*)ws;                 // 4 x 1M f16 = 8 MB
  _Float16* Qh = (_Float16*)(ws + 8 * MB);      // (B,H,S,64) f16, 8 MB
  _Float16* Kt = (_Float16*)(ws + 16 * MB);     // swizzled K tiles, 8 MB
  _Float16* Vt = (_Float16*)(ws + 24 * MB);     // swizzled V^T tiles, 8 MB
  _Float16* Wh = (_Float16*)(ws + 32 * MB);     // weight f16, 8 MB
  _Float16* AO = (_Float16*)(ws + 40 * MB);     // (B,S,1024) f16, 8 MB

  transw_kernel<<<dim3(32, 32, 4), 256, 0, stream>>>(Wq, Wk, Wv, Wo, Wt);
  wcast_kernel<<<2048, 256, 0, stream>>>(weight, Wh);
  proj_kernel<<<dim3(8, 32, 3), 256, 0, stream>>>(q, k, v, Wt, bq, bk, bv, Qh, Kt, Vt);
  attn_kernel<<<dim3(8, 64), 512, 0, stream>>>(Qh, Kt, Vt, Wh, mask, AO);
  outproj_kernel<<<dim3(8, 64), 256, 0, stream>>>(AO, Wt + 3 * (1 << 20), bo, out);
}

// Round 4
// 153.307 us; speedup vs baseline: 1.8154x; 1.1383x over previous
//
#include <hip/hip_runtime.h>
#include <hip/hip_fp16.h>

#define DEV __device__ __forceinline__

typedef _Float16 f16x8 __attribute__((ext_vector_type(8)));
typedef float f32x4 __attribute__((ext_vector_type(4)));

DEV void gload16(void* lds, const void* g) {
  __builtin_amdgcn_global_load_lds((__attribute__((address_space(1))) const void*)g,
                                   (__attribute__((address_space(3))) void*)lds,
                                   16, 0, 0);
}

DEV f32x4 mfma16(f16x8 a, f16x8 b, f32x4 c) {
  return __builtin_amdgcn_mfma_f32_16x16x32_f16(a, b, c, 0, 0, 0);
}

// ---------------- W transpose + cast: Wt[n][k] = W[k][n] (f16) ----------------
__global__ __launch_bounds__(256) void transw_kernel(
    const float* __restrict__ W0, const float* __restrict__ W1,
    const float* __restrict__ W2, const float* __restrict__ W3,
    _Float16* __restrict__ Wt) {
  __shared__ float tile[32][33];
  const float* W = (blockIdx.z == 0) ? W0 : (blockIdx.z == 1) ? W1
                 : (blockIdx.z == 2) ? W2 : W3;
  _Float16* dst = Wt + (size_t)blockIdx.z * (1024 * 1024);
  const int tx = threadIdx.x & 31, ty = threadIdx.x >> 5;
  const int n0 = blockIdx.x * 32, k0 = blockIdx.y * 32;
#pragma unroll
  for (int i = 0; i < 4; ++i)
    tile[ty + i * 8][tx] = W[(size_t)(k0 + ty + i * 8) * 1024 + n0 + tx];
  __syncthreads();
#pragma unroll
  for (int i = 0; i < 4; ++i)
    dst[(size_t)(n0 + ty + i * 8) * 1024 + k0 + tx] = (_Float16)tile[tx][ty + i * 8];
}

// ---------------- fp32 -> f16 streaming cast ----------------
__global__ __launch_bounds__(256) void wcast_kernel(const float* __restrict__ W,
                                                    _Float16* __restrict__ Wh) {
  const size_t i = (size_t)(blockIdx.x * 256 + threadIdx.x) * 8;
  float4 a = *(const float4*)(W + i);
  float4 b = *(const float4*)(W + i + 4);
  f16x8 o;
  o[0] = (_Float16)a.x; o[1] = (_Float16)a.y; o[2] = (_Float16)a.z; o[3] = (_Float16)a.w;
  o[4] = (_Float16)b.x; o[5] = (_Float16)b.y; o[6] = (_Float16)b.z; o[7] = (_Float16)b.w;
  *(f16x8*)(Wh + i) = o;
}

// q,k,v fp32 -> Ah f16 (slab z = blockIdx.y)
__global__ __launch_bounds__(256) void qkvcast_kernel(
    const float* __restrict__ q, const float* __restrict__ k,
    const float* __restrict__ v, _Float16* __restrict__ Ah) {
  const float* src = (blockIdx.y == 0) ? q : (blockIdx.y == 1) ? k : v;
  _Float16* dst = Ah + (size_t)blockIdx.y * (4096ull * 1024);
  const size_t i = (size_t)(blockIdx.x * 256 + threadIdx.x) * 8;
  float4 a = *(const float4*)(src + i);
  float4 b = *(const float4*)(src + i + 4);
  f16x8 o;
  o[0] = (_Float16)a.x; o[1] = (_Float16)a.y; o[2] = (_Float16)a.z; o[3] = (_Float16)a.w;
  o[4] = (_Float16)b.x; o[5] = (_Float16)b.y; o[6] = (_Float16)b.z; o[7] = (_Float16)b.w;
  *(f16x8*)(dst + i) = o;
}

// ---------------- shared GEMM core: C = A(MxK,f16) @ Bt(N,K)^T ----------------
// 128x128 tile, BK=32, 256 threads = 4 waves (2x2 of 64x64).
template <bool AF32>
DEV void gemm_core(const void* __restrict__ Aptr, const _Float16* __restrict__ Bt,
                   _Float16* Al, _Float16* Bl, int m0, int n0, f32x4 (&acc)[4][4]) {
  const int t = threadIdx.x;
  const int l = t & 63, w = t >> 6;
  const int wr = w >> 1, wc = w & 1;
  const int lo = l & 15, lg = l >> 4;

  for (int ks = 0; ks < 1024; ks += 32) {
    __syncthreads();
    gload16(&Bl[t * 8], Bt + (size_t)(n0 + (t >> 2)) * 1024 + ks + (t & 3) * 8);
    gload16(&Bl[(t + 256) * 8], Bt + (size_t)(n0 + (t >> 2) + 64) * 1024 + ks + (t & 3) * 8);
    if constexpr (AF32) {
      const float* Ag = (const float*)Aptr;
      const int row = t >> 1, c0 = (t & 1) * 16;
      const float4* src = (const float4*)(Ag + (size_t)(m0 + row) * 1024 + ks + c0);
      float4 f0 = src[0], f1 = src[1], f2 = src[2], f3 = src[3];
      f16x8 v0, v1;
      v0[0] = (_Float16)f0.x; v0[1] = (_Float16)f0.y; v0[2] = (_Float16)f0.z; v0[3] = (_Float16)f0.w;
      v0[4] = (_Float16)f1.x; v0[5] = (_Float16)f1.y; v0[6] = (_Float16)f1.z; v0[7] = (_Float16)f1.w;
      v1[0] = (_Float16)f2.x; v1[1] = (_Float16)f2.y; v1[2] = (_Float16)f2.z; v1[3] = (_Float16)f2.w;
      v1[4] = (_Float16)f3.x; v1[5] = (_Float16)f3.y; v1[6] = (_Float16)f3.z; v1[7] = (_Float16)f3.w;
      *(f16x8*)&Al[row * 32 + c0] = v0;
      *(f16x8*)&Al[row * 32 + c0 + 8] = v1;
    } else {
      const _Float16* Ag = (const _Float16*)Aptr;
      gload16(&Al[t * 8], Ag + (size_t)(m0 + (t >> 2)) * 1024 + ks + (t & 3) * 8);
      gload16(&Al[(t + 256) * 8], Ag + (size_t)(m0 + (t >> 2) + 64) * 1024 + ks + (t & 3) * 8);
    }
    __syncthreads();

    f16x8 af[4], bf[4];
#pragma unroll
    for (int mi = 0; mi < 4; ++mi)
      af[mi] = *(const f16x8*)&Al[(wr * 64 + mi * 16 + lo) * 32 + lg * 8];
#pragma unroll
    for (int ni = 0; ni < 4; ++ni)
      bf[ni] = *(const f16x8*)&Bl[(wc * 64 + ni * 16 + lo) * 32 + lg * 8];
#pragma unroll
    for (int mi = 0; mi < 4; ++mi)
#pragma unroll
      for (int ni = 0; ni < 4; ++ni)
        acc[mi][ni] = mfma16(af[mi], bf[ni], acc[mi][ni]);
  }
}

// ---------------- fused QKV projections, XCD-chunked swizzle ----------------
// Qh plain (B,H,S,64).  Kt: per-(b,h) slab of 16 swizzled 64x64 tiles.
// Vt: same but V^T.  AHALF: A is pre-cast f16 (gload_lds path).
template <bool AHALF>
__global__ __launch_bounds__(256) void proj_kernel(
    const _Float16* __restrict__ Ah, const float* __restrict__ qin,
    const float* __restrict__ kin, const float* __restrict__ vin,
    const _Float16* __restrict__ Wt, const float* __restrict__ bq,
    const float* __restrict__ bk, const float* __restrict__ bv,
    _Float16* __restrict__ Qh, _Float16* __restrict__ Kt,
    _Float16* __restrict__ Vt) {
  __shared__ __attribute__((aligned(16))) _Float16 Al[128 * 32];
  __shared__ __attribute__((aligned(16))) _Float16 Bl[128 * 32];
  // XCD-bijective chunked swizzle: nwg=768, 8 XCDs, chunk=96.
  const int lin = blockIdx.x + (blockIdx.y << 3) + (blockIdx.z << 8);
  const int work = (lin & 7) * 96 + (lin >> 3);
  const int z = work >> 8;
  const int m0 = ((work & 255) >> 3) * 128;
  const int n0 = (work & 7) * 128;

  const _Float16* Bt = Wt + (size_t)z * (1 << 20);
  const float* bias = (z == 0) ? bq : (z == 1) ? bk : bv;
  _Float16* C = (z == 0) ? Qh : (z == 1) ? Kt : Vt;

  f32x4 acc[4][4];
#pragma unroll
  for (int i = 0; i < 4; ++i)
#pragma unroll
    for (int j = 0; j < 4; ++j) acc[i][j] = (f32x4){0.f, 0.f, 0.f, 0.f};
  if constexpr (AHALF) {
    gemm_core<false>(Ah + (size_t)z * (4096ull * 1024), Bt, Al, Bl, m0, n0, acc);
  } else {
    const float* A = (z == 0) ? qin : (z == 1) ? kin : vin;
    gemm_core<true>(A, Bt, Al, Bl, m0, n0, acc);
  }

  const int l = threadIdx.x & 63, w = threadIdx.x >> 6;
  const int wr = w >> 1, wc = w & 1;
  const int lo = l & 15, lg = l >> 4;
#pragma unroll
  for (int mi = 0; mi < 4; ++mi) {
#pragma unroll
    for (int ni = 0; ni < 4; ++ni) {
      const int col = n0 + wc * 64 + ni * 16 + lo;
      const int rowb = m0 + wr * 64 + mi * 16 + lg * 4;
      const float bc = bias[col];
      const int h = col >> 6, d = col & 63;
#pragma unroll
      for (int r = 0; r < 4; ++r) {
        const float vv = acc[mi][ni][r] + bc;
        const int m = rowb + r;
        const int b = m >> 10, s = m & 1023;
        const size_t slab = (size_t)(b * 16 + h) * 65536;
        if (z == 0) {
          C[slab + (size_t)s * 64 + d] = (_Float16)vv;
        } else if (z == 1) {
          // K tile: row = s&63, elem d at slot (d>>3)^(row&7)
          C[slab + (size_t)(s >> 6) * 4096 + (size_t)(s & 63) * 64 +
            (((d >> 3) ^ (s & 7)) << 3) + (d & 7)] = (_Float16)vv;
        } else {
          // V^T tile: row = d, col c = s&63 at slot (c>>3)^(d&7)
          C[slab + (size_t)(s >> 6) * 4096 + (size_t)d * 64 +
            ((((s >> 3) & 7) ^ (d & 7)) << 3) + (s & 7)] = (_Float16)vv;
        }
      }
    }
  }
}

// ---------------- output projection: out(f32) = AO @ Wo^T + bo ----------------
__global__ __launch_bounds__(256) void outproj_kernel(
    const _Float16* __restrict__ AO, const _Float16* __restrict__ Bt,
    const float* __restrict__ bias, float* __restrict__ out) {
  __shared__ __attribute__((aligned(16))) _Float16 Al[128 * 32];
  __shared__ __attribute__((aligned(16))) _Float16 Bl[128 * 32];
  // nwg=256, chunk=32
  const int lin = blockIdx.x + (blockIdx.y << 3);
  const int work = (lin & 7) * 32 + (lin >> 3);
  const int m0 = (work >> 3) * 128;
  const int n0 = (work & 7) * 128;
  f32x4 acc[4][4];
#pragma unroll
  for (int i = 0; i < 4; ++i)
#pragma unroll
    for (int j = 0; j < 4; ++j) acc[i][j] = (f32x4){0.f, 0.f, 0.f, 0.f};
  gemm_core<false>(AO, Bt, Al, Bl, m0, n0, acc);

  const int l = threadIdx.x & 63, w = threadIdx.x >> 6;
  const int wr = w >> 1, wc = w & 1;
  const int lo = l & 15, lg = l >> 4;
#pragma unroll
  for (int mi = 0; mi < 4; ++mi) {
#pragma unroll
    for (int ni = 0; ni < 4; ++ni) {
      const int col = n0 + wc * 64 + ni * 16 + lo;
      const int rowb = m0 + wr * 64 + mi * 16 + lg * 4;
      const float bc = bias[col];
#pragma unroll
      for (int r = 0; r < 4; ++r)
        out[(size_t)(rowb + r) * 1024 + col] = acc[mi][ni][r] + bc;
    }
  }
}

// ---------------- Flash attention v3 (unchanged from round 3) ----------------
__global__ __launch_bounds__(512, 4) void attn_kernel(
    const _Float16* __restrict__ Qh, const _Float16* __restrict__ Kt,
    const _Float16* __restrict__ Vt, const _Float16* __restrict__ Wh,
    const float* __restrict__ mask, _Float16* __restrict__ AO) {
  __shared__ __attribute__((aligned(16))) _Float16 Kl[2][4096];
  __shared__ __attribute__((aligned(16))) _Float16 Vl[2][4096];
  __shared__ __attribute__((aligned(16))) _Float16 Pl[8][16][72];
  const int t = threadIdx.x, l = t & 63, w = t >> 6;
  const int lo = l & 15, lg = l >> 4;
  const int bh = blockIdx.y, b = bh >> 4, h = bh & 15;
  const int q0w = blockIdx.x * 128 + w * 16;
  constexpr float L2E = 1.44269504089f;
  const float scale = 0.1f + (float)h * (9.9f / 15.0f);
  const float cS = 0.125f * L2E;
  const float cW = scale * L2E;
  const float cM = -1e9f * L2E;
  const _Float16* Kslab = Kt + (size_t)bh * 65536;
  const _Float16* Vslab = Vt + (size_t)bh * 65536;
  const _Float16* Wb = Wh + ((size_t)b << 20);
  const float* Mb = mask + (size_t)b * 1024;
  const int qrow = q0w + lg * 4;

  const f16x8 qf0 = *(const f16x8*)(Qh + (size_t)bh * 65536 + (q0w + lo) * 64 + lg * 8);
  const f16x8 qf1 = *(const f16x8*)(Qh + (size_t)bh * 65536 + (q0w + lo) * 64 + 32 + lg * 8);

  f32x4 oacc[4];
#pragma unroll
  for (int di = 0; di < 4; ++di) oacc[di] = (f32x4){0.f, 0.f, 0.f, 0.f};
  float mrun[4], lsum[4];
#pragma unroll
  for (int r = 0; r < 4; ++r) { mrun[r] = -1e38f; lsum[r] = 0.f; }

  gload16(&Kl[0][t * 8], Kslab + t * 8);
  gload16(&Vl[0][t * 8], Vslab + t * 8);
  __syncthreads();

  for (int kt = 0; kt < 16; ++kt) {
    const int cur = kt & 1;
    if (kt + 1 < 16) {
      gload16(&Kl[cur ^ 1][t * 8], Kslab + (size_t)(kt + 1) * 4096 + t * 8);
      gload16(&Vl[cur ^ 1][t * 8], Vslab + (size_t)(kt + 1) * 4096 + t * 8);
    }
    const int kv0 = kt * 64;
    const _Float16* Kb = Kl[cur];
    const _Float16* Vb = Vl[cur];
    const int sl = lg ^ (lo & 7);

    float sv[4][4];
    float tm[4] = {-1e38f, -1e38f, -1e38f, -1e38f};
#pragma unroll
    for (int ni = 0; ni < 4; ++ni) {
      const int key = kv0 + ni * 16 + lo;
      const float mkv = Mb[key] * cM;
      float wgt[4];
#pragma unroll
      for (int r = 0; r < 4; ++r)
        wgt[r] = (float)Wb[(size_t)(qrow + r) * 1024 + key];
      const int kr = ni * 16 + lo;
      f16x8 kf0 = *(const f16x8*)(Kb + kr * 64 + sl * 8);
      f16x8 kf1 = *(const f16x8*)(Kb + kr * 64 + (sl ^ 4) * 8);
      f32x4 s = (f32x4){0.f, 0.f, 0.f, 0.f};
      s = mfma16(qf0, kf0, s);
      s = mfma16(qf1, kf1, s);
#pragma unroll
      for (int r = 0; r < 4; ++r) {
        const float x = s[r] * cS + wgt[r] * cW + mkv;
        sv[ni][r] = x;
        tm[r] = fmaxf(tm[r], x);
      }
    }
#pragma unroll
    for (int st = 1; st < 16; st <<= 1)
#pragma unroll
      for (int r = 0; r < 4; ++r) tm[r] = fmaxf(tm[r], __shfl_xor(tm[r], st));
    float fr[4];
#pragma unroll
    for (int r = 0; r < 4; ++r) {
      const float mn = fmaxf(mrun[r], tm[r]);
      fr[r] = exp2f(mrun[r] - mn);
      mrun[r] = mn;
      lsum[r] *= fr[r];
    }
#pragma unroll
    for (int di = 0; di < 4; ++di)
#pragma unroll
      for (int r = 0; r < 4; ++r) oacc[di][r] *= fr[r];
#pragma unroll
    for (int ni = 0; ni < 4; ++ni)
#pragma unroll
      for (int r = 0; r < 4; ++r) {
        const float p = exp2f(sv[ni][r] - mrun[r]);
        lsum[r] += p;
        Pl[w][lg * 4 + r][ni * 16 + lo] = (_Float16)p;
      }
    const f16x8 pa0 = *(const f16x8*)(&Pl[w][lo][lg * 8]);
    const f16x8 pa1 = *(const f16x8*)(&Pl[w][lo][32 + lg * 8]);
    __builtin_amdgcn_s_setprio(1);
#pragma unroll
    for (int di = 0; di < 4; ++di) {
      const int d = di * 16 + lo;
      f16x8 vf0 = *(const f16x8*)(Vb + d * 64 + sl * 8);
      f16x8 vf1 = *(const f16x8*)(Vb + d * 64 + (sl ^ 4) * 8);
      oacc[di] = mfma16(pa0, vf0, oacc[di]);
      oacc[di] = mfma16(pa1, vf1, oacc[di]);
    }
    __builtin_amdgcn_s_setprio(0);
    __syncthreads();
  }

#pragma unroll
  for (int st = 1; st < 16; st <<= 1)
#pragma unroll
    for (int r = 0; r < 4; ++r) lsum[r] += __shfl_xor(lsum[r], st);
#pragma unroll
  for (int r = 0; r < 4; ++r) {
    const float inv = 1.0f / lsum[r];
#pragma unroll
    for (int di = 0; di < 4; ++di)
      AO[((size_t)(b * 1024) + qrow + r) * 1024 + h * 64 + di * 16 + lo] =
          (_Float16)(oacc[di][r] * inv);
  }
}

extern "C" void kernel_launch(void* const* d_in, const int* in_sizes, int n_in,
                              void* d_out, int out_size, void* d_ws, size_t ws_size,
                              hipStream_t stream) {
  (void)in_sizes; (void)n_in; (void)out_size;
  const float* v      = (const float*)d_in[0];
  const float* k      = (const float*)d_in[1];
  const float* q      = (const float*)d_in[2];
  const float* weight = (const float*)d_in[3];
  const float* mask   = (const float*)d_in[4];
  const float* Wq = (const float*)d_in[5];
  const float* bq = (const float*)d_in[6];
  const float* Wk = (const float*)d_in[7];
  const float* bk = (const float*)d_in[8];
  const float* Wv = (const float*)d_in[9];
  const float* bv = (const float*)d_in[10];
  const float* Wo = (const float*)d_in[11];
  const float* bo = (const float*)d_in[12];
  float* out = (float*)d_out;

  const size_t MB = 1ull << 20;
  char* ws = (char*)d_ws;
  _Float16* Wt = (_Float16*)ws;                 // 4 x 1M f16 = 8 MB
  _Float16* Qh = (_Float16*)(ws + 8 * MB);      // (B,H,S,64) f16, 8 MB
  _Float16* Kt = (_Float16*)(ws + 16 * MB);     // swizzled K tiles, 8 MB
  _Float16* Vt = (_Float16*)(ws + 24 * MB);     // swizzled V^T tiles, 8 MB
  _Float16* Wh = (_Float16*)(ws + 32 * MB);     // weight f16, 8 MB
  _Float16* AO = (_Float16*)(ws + 40 * MB);     // (B,S,1024) f16, 8 MB
  _Float16* Ah = (_Float16*)(ws + 40 * MB);     // f16 qkv, 24 MB (dead before AO born)

  transw_kernel<<<dim3(32, 32, 4), 256, 0, stream>>>(Wq, Wk, Wv, Wo, Wt);
  wcast_kernel<<<2048, 256, 0, stream>>>(weight, Wh);
  if (ws_size >= 64 * MB) {
    qkvcast_kernel<<<dim3(2048, 3), 256, 0, stream>>>(q, k, v, Ah);
    proj_kernel<true><<<dim3(8, 32, 3), 256, 0, stream>>>(Ah, q, k, v, Wt, bq, bk, bv,
                                                          Qh, Kt, Vt);
  } else {
    proj_kernel<false><<<dim3(8, 32, 3), 256, 0, stream>>>(nullptr, q, k, v, Wt, bq, bk,
                                                           bv, Qh, Kt, Vt);
  }
  attn_kernel<<<dim3(8, 64), 512, 0, stream>>>(Qh, Kt, Vt, Wh, mask, AO);
  outproj_kernel<<<dim3(8, 32), 256, 0, stream>>>(AO, Wt + 3 * (1 << 20), bo, out);
}